// Round 1
// baseline (724.139 us; speedup 1.0000x reference)
//
#include <hip/hip_runtime.h>

#define N_NODES 50000
#define N_EDGES 1600000
#define FIN 256
#define HD 128          // HEADS*HIDDEN
#define NHEADS 4
#define C2 16           // NUM_CLASSES
#define NEG 0.2f
#define NCH 98          // ceil(50000/512)

__device__ __forceinline__ float elu1(float x) { return x > 0.f ? x : __expf(x) - 1.f; }

// ---------------- CSR build ----------------

__global__ void k_hist(const int* __restrict__ dst, int* __restrict__ deg) {
    int i = blockIdx.x * blockDim.x + threadIdx.x;
    int stride = gridDim.x * blockDim.x;
    for (; i < N_EDGES; i += stride) atomicAdd(&deg[dst[i]], 1);
}

__global__ void k_chunksum(const int* __restrict__ deg, int* __restrict__ chunksum) {
    __shared__ int s[256];
    int b = blockIdx.x, t = threadIdx.x;
    int i0 = b * 512 + t, i1 = i0 + 256;
    int v = 0;
    if (i0 < N_NODES) v += deg[i0];
    if (i1 < N_NODES) v += deg[i1];
    s[t] = v; __syncthreads();
    for (int off = 128; off > 0; off >>= 1) {
        if (t < off) s[t] += s[t + off];
        __syncthreads();
    }
    if (t == 0) chunksum[b] = s[0];
}

__global__ void k_scanchunks(const int* __restrict__ chunksum, int* __restrict__ chunkoff) {
    __shared__ int s[128];
    int t = threadIdx.x;  // blockDim = 128
    int v = (t < NCH) ? chunksum[t] : 0;
    s[t] = v; __syncthreads();
    for (int off = 1; off < 128; off <<= 1) {
        int u = (t >= off) ? s[t - off] : 0;
        __syncthreads();
        s[t] += u;
        __syncthreads();
    }
    chunkoff[t] = s[t] - v;  // exclusive
}

__global__ void k_scanfinal(const int* __restrict__ deg, const int* __restrict__ chunkoff,
                            int* __restrict__ rowstart, int* __restrict__ cursor) {
    __shared__ int s[256];
    int b = blockIdx.x, t = threadIdx.x;
    int i0 = b * 512 + 2 * t, i1 = i0 + 1;
    int a0 = (i0 < N_NODES) ? deg[i0] : 0;
    int a1 = (i1 < N_NODES) ? deg[i1] : 0;
    int pair = a0 + a1;
    s[t] = pair; __syncthreads();
    for (int off = 1; off < 256; off <<= 1) {
        int u = (t >= off) ? s[t - off] : 0;
        __syncthreads();
        s[t] += u;
        __syncthreads();
    }
    int excl = s[t] - pair + chunkoff[b];
    if (i0 <= N_NODES) { rowstart[i0] = excl; if (i0 < N_NODES) cursor[i0] = excl; }
    int e1 = excl + a0;
    if (i1 <= N_NODES) { rowstart[i1] = e1; if (i1 < N_NODES) cursor[i1] = e1; }
}

__global__ void k_scatter(const int* __restrict__ src, const int* __restrict__ dst,
                          int* __restrict__ cursor, int* __restrict__ sorted_src) {
    int i = blockIdx.x * blockDim.x + threadIdx.x;
    int stride = gridDim.x * blockDim.x;
    for (; i < N_EDGES; i += stride) {
        int d = dst[i];
        int pos = atomicAdd(&cursor[d], 1);
        sorted_src[pos] = src[i];
    }
}

// ---------------- Layer 1 GEMM: feat1 = x @ W1, fused el1/er1 ----------------

__global__ void k_trans(const float* __restrict__ W1, float* __restrict__ W1T) {
    int idx = blockIdx.x * blockDim.x + threadIdx.x;  // 32768 total
    if (idx < FIN * HD) {
        int k = idx >> 7, c = idx & 127;
        W1T[c * FIN + k] = W1[idx];
    }
}

__global__ __launch_bounds__(256) void k_gemm1(
        const float* __restrict__ x, const float* __restrict__ W1T,
        const float* __restrict__ al1, const float* __restrict__ ar1,
        float* __restrict__ feat1, float* __restrict__ el1, float* __restrict__ er1) {
    __shared__ float4 xs[8 * 64];  // 8 node rows x 256 floats
    int tid = threadIdx.x;
    int nb = blockIdx.x * 8;       // 50000 % 8 == 0 -> no guards
    const float4* x4 = (const float4*)x;
    for (int idx = tid; idx < 512; idx += 256) {
        int row = idx >> 6, kk = idx & 63;
        xs[row * 64 + kk] = x4[(size_t)(nb + row) * 64 + kk];
    }
    __syncthreads();
    int col = tid & 127, half = tid >> 7;
    const float4* wrow = (const float4*)(W1T + col * FIN);
    float acc[4] = {0.f, 0.f, 0.f, 0.f};
    const float4* xr = &xs[(half * 4) * 64];
    #pragma unroll 4
    for (int kk = 0; kk < 64; kk++) {
        float4 w = wrow[kk];
        #pragma unroll
        for (int n = 0; n < 4; n++) {
            float4 v = xr[n * 64 + kk];
            acc[n] += w.x * v.x + w.y * v.y + w.z * v.z + w.w * v.w;
        }
    }
    float alv = al1[col], arv = ar1[col];
    int head = col >> 5;
    int lane = tid & 63;
    #pragma unroll
    for (int n = 0; n < 4; n++) {
        int node = nb + half * 4 + n;
        feat1[(size_t)node * HD + col] = acc[n];
        float pl = acc[n] * alv, pr = acc[n] * arv;
        #pragma unroll
        for (int m = 16; m >= 1; m >>= 1) {
            pl += __shfl_xor(pl, m);
            pr += __shfl_xor(pr, m);
        }
        if ((lane & 31) == 0) { el1[node * 4 + head] = pl; er1[node * 4 + head] = pr; }
    }
}

// ---------------- Layer 1 aggregation: one wave per dst node ----------------
// out1[d] = sum_e alpha * feat1[src];  h = elu(out1 + b1)

__global__ __launch_bounds__(256) void k_agg1(
        const int* __restrict__ rowstart, const int* __restrict__ sorted_src,
        const float* __restrict__ el1, const float* __restrict__ er1,
        const float* __restrict__ feat1, const float* __restrict__ b1,
        float* __restrict__ h) {
    int tid = threadIdx.x;
    int d = blockIdx.x * 4 + (tid >> 6);   // 50000 % 4 == 0
    int lane = tid & 63;
    int head = lane >> 4;                  // lane covers cols [2*lane, 2*lane+1]
    float er = er1[d * 4 + head];
    int start = rowstart[d], end = rowstart[d + 1];
    float ax = 0.f, ay = 0.f, wsum = 0.f;
    const float2* fbase = (const float2*)feat1;
    for (int i = start; i < end; i++) {
        int s = sorted_src[i];
        float e = el1[s * 4 + head] + er;
        float w = __expf(e > 0.f ? e : NEG * e);
        float2 f = fbase[(size_t)s * 64 + lane];
        ax += w * f.x; ay += w * f.y; wsum += w;
    }
    float inv = 1.f / fmaxf(wsum, 1e-9f);
    int c = lane * 2;
    float vx = elu1(ax * inv + b1[c]);
    float vy = elu1(ay * inv + b1[c + 1]);
    ((float2*)h)[(size_t)d * 64 + lane] = make_float2(vx, vy);
}

// ---------------- Layer 2 GEMM: feat2 = h @ W2, fused el2/er2 ----------------

__global__ __launch_bounds__(256) void k_gemm2(
        const float* __restrict__ h, const float* __restrict__ W2,
        const float* __restrict__ al2, const float* __restrict__ ar2,
        float* __restrict__ feat2, float* __restrict__ el2, float* __restrict__ er2) {
    __shared__ float hs[16 * 132];
    __shared__ float w2t[16 * 132];
    int tid = threadIdx.x;
    int nb = blockIdx.x * 16;  // 50000 % 16 == 0
    for (int idx = tid; idx < 512; idx += 256) {
        int row = idx >> 5, kk = idx & 31;
        ((float4*)(hs + row * 132))[kk] = ((const float4*)h)[(size_t)(nb + row) * 32 + kk];
    }
    for (int idx = tid; idx < 2048; idx += 256) {
        int k = idx >> 4, c = idx & 15;
        w2t[c * 132 + k] = W2[idx];
    }
    __syncthreads();
    int nl = tid >> 4, col = tid & 15;
    const float4* hv = (const float4*)(hs + nl * 132);
    const float4* wv = (const float4*)(w2t + col * 132);
    float acc = 0.f;
    #pragma unroll
    for (int kk = 0; kk < 32; kk++) {
        float4 a = hv[kk], w = wv[kk];
        acc += a.x * w.x + a.y * w.y + a.z * w.z + a.w * w.w;
    }
    int node = nb + nl;
    feat2[node * 16 + col] = acc;
    float pl = acc * al2[col], pr = acc * ar2[col];
    #pragma unroll
    for (int m = 8; m >= 1; m >>= 1) {
        pl += __shfl_xor(pl, m);
        pr += __shfl_xor(pr, m);
    }
    if (col == 0) { el2[node] = pl; er2[node] = pr; }
}

// ---------------- Layer 2 aggregation: 16 lanes per dst node ----------------

__global__ __launch_bounds__(256) void k_agg2(
        const int* __restrict__ rowstart, const int* __restrict__ sorted_src,
        const float* __restrict__ el2, const float* __restrict__ er2,
        const float* __restrict__ feat2, const float* __restrict__ b2,
        float* __restrict__ out) {
    int tid = threadIdx.x;
    int d = blockIdx.x * 16 + (tid >> 4);  // 50000 % 16 == 0
    int col = tid & 15;
    float er = er2[d];
    int start = rowstart[d], end = rowstart[d + 1];
    float acc = 0.f, wsum = 0.f;
    for (int i = start; i < end; i++) {
        int s = sorted_src[i];
        float e = el2[s] + er;
        float w = __expf(e > 0.f ? e : NEG * e);
        acc += w * feat2[s * 16 + col];
        wsum += w;
    }
    out[d * 16 + col] = acc / fmaxf(wsum, 1e-9f) + b2[col];
}

// ---------------- launch ----------------

extern "C" void kernel_launch(void* const* d_in, const int* in_sizes, int n_in,
                              void* d_out, int out_size, void* d_ws, size_t ws_size,
                              hipStream_t stream) {
    const float* x   = (const float*)d_in[0];
    const int*   src = (const int*)d_in[1];
    const int*   dst = (const int*)d_in[2];
    const float* W1  = (const float*)d_in[3];
    const float* b1  = (const float*)d_in[4];
    const float* al1 = (const float*)d_in[5];
    const float* ar1 = (const float*)d_in[6];
    const float* W2  = (const float*)d_in[7];
    const float* b2  = (const float*)d_in[8];
    const float* al2 = (const float*)d_in[9];
    const float* ar2 = (const float*)d_in[10];
    float* out = (float*)d_out;

    char* ws = (char*)d_ws;
    size_t off = 0;
    auto alloc = [&](size_t bytes) -> char* {
        char* p = ws + off;
        off += (bytes + 255) & ~(size_t)255;
        return p;
    };
    float* feat1      = (float*)alloc((size_t)N_NODES * HD * 4);
    float* h          = (float*)alloc((size_t)N_NODES * HD * 4);
    float* el1        = (float*)alloc((size_t)N_NODES * 4 * 4);
    float* er1        = (float*)alloc((size_t)N_NODES * 4 * 4);
    float* feat2      = (float*)alloc((size_t)N_NODES * C2 * 4);
    float* el2        = (float*)alloc((size_t)N_NODES * 4);
    float* er2        = (float*)alloc((size_t)N_NODES * 4);
    float* W1T        = (float*)alloc((size_t)FIN * HD * 4);
    int*   deg        = (int*)alloc((size_t)N_NODES * 4);
    int*   rowstart   = (int*)alloc((size_t)(N_NODES + 1) * 4);
    int*   cursor     = (int*)alloc((size_t)N_NODES * 4);
    int*   chunksum   = (int*)alloc(128 * 4);
    int*   chunkoff   = (int*)alloc(128 * 4);
    int*   sorted_src = (int*)alloc((size_t)N_EDGES * 4);

    hipMemsetAsync(deg, 0, (size_t)N_NODES * 4, stream);
    k_hist<<<2048, 256, 0, stream>>>(dst, deg);
    k_chunksum<<<NCH, 256, 0, stream>>>(deg, chunksum);
    k_scanchunks<<<1, 128, 0, stream>>>(chunksum, chunkoff);
    k_scanfinal<<<NCH, 256, 0, stream>>>(deg, chunkoff, rowstart, cursor);
    k_scatter<<<2048, 256, 0, stream>>>(src, dst, cursor, sorted_src);
    k_trans<<<128, 256, 0, stream>>>(W1, W1T);
    k_gemm1<<<N_NODES / 8, 256, 0, stream>>>(x, W1T, al1, ar1, feat1, el1, er1);
    k_agg1<<<N_NODES / 4, 256, 0, stream>>>(rowstart, sorted_src, el1, er1, feat1, b1, h);
    k_gemm2<<<N_NODES / 16, 256, 0, stream>>>(h, W2, al2, ar2, feat2, el2, er2);
    k_agg2<<<N_NODES / 16, 256, 0, stream>>>(rowstart, sorted_src, el2, er2, feat2, b2, out);
}

// Round 2
// 576.194 us; speedup vs baseline: 1.2568x; 1.2568x over previous
//
#include <hip/hip_runtime.h>

#define N_NODES 50000
#define N_EDGES 1600000
#define FIN 256
#define HD 128          // HEADS*HIDDEN
#define NHEADS 4
#define C2 16           // NUM_CLASSES
#define NEG 0.2f
#define NCH 98          // ceil(50000/512)

__device__ __forceinline__ float elu1(float x) { return x > 0.f ? x : __expf(x) - 1.f; }

// ---------------- CSR build ----------------

__global__ void k_hist(const int* __restrict__ dst, int* __restrict__ deg) {
    int i = blockIdx.x * blockDim.x + threadIdx.x;
    int stride = gridDim.x * blockDim.x;
    for (; i < N_EDGES; i += stride) atomicAdd(&deg[dst[i]], 1);
}

__global__ void k_chunksum(const int* __restrict__ deg, int* __restrict__ chunksum) {
    __shared__ int s[256];
    int b = blockIdx.x, t = threadIdx.x;
    int i0 = b * 512 + t, i1 = i0 + 256;
    int v = 0;
    if (i0 < N_NODES) v += deg[i0];
    if (i1 < N_NODES) v += deg[i1];
    s[t] = v; __syncthreads();
    for (int off = 128; off > 0; off >>= 1) {
        if (t < off) s[t] += s[t + off];
        __syncthreads();
    }
    if (t == 0) chunksum[b] = s[0];
}

__global__ void k_scanchunks(const int* __restrict__ chunksum, int* __restrict__ chunkoff) {
    __shared__ int s[128];
    int t = threadIdx.x;  // blockDim = 128
    int v = (t < NCH) ? chunksum[t] : 0;
    s[t] = v; __syncthreads();
    for (int off = 1; off < 128; off <<= 1) {
        int u = (t >= off) ? s[t - off] : 0;
        __syncthreads();
        s[t] += u;
        __syncthreads();
    }
    chunkoff[t] = s[t] - v;  // exclusive
}

__global__ void k_scanfinal(const int* __restrict__ deg, const int* __restrict__ chunkoff,
                            int* __restrict__ rowstart, int* __restrict__ cursor) {
    __shared__ int s[256];
    int b = blockIdx.x, t = threadIdx.x;
    int i0 = b * 512 + 2 * t, i1 = i0 + 1;
    int a0 = (i0 < N_NODES) ? deg[i0] : 0;
    int a1 = (i1 < N_NODES) ? deg[i1] : 0;
    int pair = a0 + a1;
    s[t] = pair; __syncthreads();
    for (int off = 1; off < 256; off <<= 1) {
        int u = (t >= off) ? s[t - off] : 0;
        __syncthreads();
        s[t] += u;
        __syncthreads();
    }
    int excl = s[t] - pair + chunkoff[b];
    if (i0 <= N_NODES) { rowstart[i0] = excl; if (i0 < N_NODES) cursor[i0] = excl; }
    int e1 = excl + a0;
    if (i1 <= N_NODES) { rowstart[i1] = e1; if (i1 < N_NODES) cursor[i1] = e1; }
}

__global__ void k_scatter(const int* __restrict__ src, const int* __restrict__ dst,
                          int* __restrict__ cursor, int* __restrict__ sorted_src) {
    int i = blockIdx.x * blockDim.x + threadIdx.x;
    int stride = gridDim.x * blockDim.x;
    for (; i < N_EDGES; i += stride) {
        int d = dst[i];
        int pos = atomicAdd(&cursor[d], 1);
        sorted_src[pos] = src[i];
    }
}

// ---------------- Layer 1 GEMM: feat1 = x @ W1, fused el1/er1 ----------------
// BM=128 nodes x BN=128 cols (all) x BK=16. 256 threads, 8x8 register tile.
// W1 consumed in native [K][col] layout (no transpose kernel needed).

__global__ __launch_bounds__(256) void k_gemm1(
        const float* __restrict__ x, const float* __restrict__ W1,
        const float* __restrict__ al1, const float* __restrict__ ar1,
        float* __restrict__ feat1, float* __restrict__ el1, float* __restrict__ er1) {
    __shared__ float xs[16 * 128];   // [kk][node] transposed x tile, 8 KB
    __shared__ float ws[16 * 128];   // [kk][col]  native W1 tile,   8 KB
    int tid = threadIdx.x;
    int nb = blockIdx.x * 128;
    int ct = tid & 15;               // col-thread: cols ct*8 .. ct*8+7
    int nt = tid >> 4;               // node-thread: nodes nt*8 .. nt*8+7

    float acc[8][8];
    #pragma unroll
    for (int n = 0; n < 8; n++)
        #pragma unroll
        for (int c = 0; c < 8; c++) acc[n][c] = 0.f;

    // staging roles
    int lnode = tid & 127;
    int kg = tid >> 7;               // 0/1: which 8 of the 16 k's this thread stages
    int gnode = nb + lnode; if (gnode >= N_NODES) gnode = N_NODES - 1;  // clamp (stores guarded)
    const float4* xrow = (const float4*)(x + (size_t)gnode * FIN);
    const float4* W14 = (const float4*)W1;

    for (int k0 = 0; k0 < FIN; k0 += 16) {
        // global loads for next tile
        float4 a0 = xrow[(k0 >> 2) + kg * 2];
        float4 a1 = xrow[(k0 >> 2) + kg * 2 + 1];
        float4 w0 = W14[(size_t)k0 * 32 + tid];
        float4 w1 = W14[(size_t)k0 * 32 + tid + 256];
        __syncthreads();             // previous tile's compute done before overwrite
        int kb = kg * 8;
        xs[(kb + 0) * 128 + lnode] = a0.x;
        xs[(kb + 1) * 128 + lnode] = a0.y;
        xs[(kb + 2) * 128 + lnode] = a0.z;
        xs[(kb + 3) * 128 + lnode] = a0.w;
        xs[(kb + 4) * 128 + lnode] = a1.x;
        xs[(kb + 5) * 128 + lnode] = a1.y;
        xs[(kb + 6) * 128 + lnode] = a1.z;
        xs[(kb + 7) * 128 + lnode] = a1.w;
        ((float4*)ws)[tid] = w0;
        ((float4*)ws)[tid + 256] = w1;
        __syncthreads();
        #pragma unroll
        for (int kk = 0; kk < 16; kk++) {
            float4 xa = ((const float4*)xs)[kk * 32 + nt * 2];
            float4 xb = ((const float4*)xs)[kk * 32 + nt * 2 + 1];
            float4 wa = ((const float4*)ws)[kk * 32 + ct * 2];
            float4 wb = ((const float4*)ws)[kk * 32 + ct * 2 + 1];
            float xn[8] = {xa.x, xa.y, xa.z, xa.w, xb.x, xb.y, xb.z, xb.w};
            float wc[8] = {wa.x, wa.y, wa.z, wa.w, wb.x, wb.y, wb.z, wb.w};
            #pragma unroll
            for (int n = 0; n < 8; n++)
                #pragma unroll
                for (int c = 0; c < 8; c++)
                    acc[n][c] += xn[n] * wc[c];
        }
    }

    // epilogue: feat1 stores + fused el/er (per-head dot + cross-lane reduce)
    float alv[8], arv[8];
    #pragma unroll
    for (int c = 0; c < 8; c++) { alv[c] = al1[ct * 8 + c]; arv[c] = ar1[ct * 8 + c]; }
    int head = ct >> 2;
    #pragma unroll
    for (int n = 0; n < 8; n++) {
        int node = nb + nt * 8 + n;
        bool ok = node < N_NODES;
        if (ok) {
            float4* fp = (float4*)(feat1 + (size_t)node * HD + ct * 8);
            fp[0] = make_float4(acc[n][0], acc[n][1], acc[n][2], acc[n][3]);
            fp[1] = make_float4(acc[n][4], acc[n][5], acc[n][6], acc[n][7]);
        }
        float pl = 0.f, pr = 0.f;
        #pragma unroll
        for (int c = 0; c < 8; c++) { pl += acc[n][c] * alv[c]; pr += acc[n][c] * arv[c]; }
        // reduce across the 4 col-threads of this head (ct bits 0..1 == lane bits 0..1)
        pl += __shfl_xor(pl, 1); pl += __shfl_xor(pl, 2);
        pr += __shfl_xor(pr, 1); pr += __shfl_xor(pr, 2);
        if (ok && (ct & 3) == 0) {
            el1[node * 4 + head] = pl;
            er1[node * 4 + head] = pr;
        }
    }
}

// ---------------- Layer 1 aggregation: one wave per dst node ----------------
// out1[d] = sum_e alpha * feat1[src];  h = elu(out1 + b1)

__global__ __launch_bounds__(256) void k_agg1(
        const int* __restrict__ rowstart, const int* __restrict__ sorted_src,
        const float* __restrict__ el1, const float* __restrict__ er1,
        const float* __restrict__ feat1, const float* __restrict__ b1,
        float* __restrict__ h) {
    int tid = threadIdx.x;
    int d = blockIdx.x * 4 + (tid >> 6);   // 50000 % 4 == 0
    int lane = tid & 63;
    int head = lane >> 4;                  // lane covers cols [2*lane, 2*lane+1]
    float er = er1[d * 4 + head];
    int start = rowstart[d], end = rowstart[d + 1];
    float ax = 0.f, ay = 0.f, wsum = 0.f;
    const float2* fbase = (const float2*)feat1;
    for (int i = start; i < end; i++) {
        int s = sorted_src[i];
        float e = el1[s * 4 + head] + er;
        float w = __expf(e > 0.f ? e : NEG * e);
        float2 f = fbase[(size_t)s * 64 + lane];
        ax += w * f.x; ay += w * f.y; wsum += w;
    }
    float inv = 1.f / fmaxf(wsum, 1e-9f);
    int c = lane * 2;
    float vx = elu1(ax * inv + b1[c]);
    float vy = elu1(ay * inv + b1[c + 1]);
    ((float2*)h)[(size_t)d * 64 + lane] = make_float2(vx, vy);
}

// ---------------- Layer 2 GEMM: feat2 = h @ W2, fused el2/er2 ----------------

__global__ __launch_bounds__(256) void k_gemm2(
        const float* __restrict__ h, const float* __restrict__ W2,
        const float* __restrict__ al2, const float* __restrict__ ar2,
        float* __restrict__ feat2, float* __restrict__ el2, float* __restrict__ er2) {
    __shared__ float hs[16 * 132];
    __shared__ float w2t[16 * 132];
    int tid = threadIdx.x;
    int nb = blockIdx.x * 16;  // 50000 % 16 == 0
    for (int idx = tid; idx < 512; idx += 256) {
        int row = idx >> 5, kk = idx & 31;
        ((float4*)(hs + row * 132))[kk] = ((const float4*)h)[(size_t)(nb + row) * 32 + kk];
    }
    for (int idx = tid; idx < 2048; idx += 256) {
        int k = idx >> 4, c = idx & 15;
        w2t[c * 132 + k] = W2[idx];
    }
    __syncthreads();
    int nl = tid >> 4, col = tid & 15;
    const float4* hv = (const float4*)(hs + nl * 132);
    const float4* wv = (const float4*)(w2t + col * 132);
    float acc = 0.f;
    #pragma unroll
    for (int kk = 0; kk < 32; kk++) {
        float4 a = hv[kk], w = wv[kk];
        acc += a.x * w.x + a.y * w.y + a.z * w.z + a.w * w.w;
    }
    int node = nb + nl;
    feat2[node * 16 + col] = acc;
    float pl = acc * al2[col], pr = acc * ar2[col];
    #pragma unroll
    for (int m = 8; m >= 1; m >>= 1) {
        pl += __shfl_xor(pl, m);
        pr += __shfl_xor(pr, m);
    }
    if (col == 0) { el2[node] = pl; er2[node] = pr; }
}

// ---------------- Layer 2 aggregation: 16 lanes per dst node ----------------

__global__ __launch_bounds__(256) void k_agg2(
        const int* __restrict__ rowstart, const int* __restrict__ sorted_src,
        const float* __restrict__ el2, const float* __restrict__ er2,
        const float* __restrict__ feat2, const float* __restrict__ b2,
        float* __restrict__ out) {
    int tid = threadIdx.x;
    int d = blockIdx.x * 16 + (tid >> 4);  // 50000 % 16 == 0
    int col = tid & 15;
    float er = er2[d];
    int start = rowstart[d], end = rowstart[d + 1];
    float acc = 0.f, wsum = 0.f;
    for (int i = start; i < end; i++) {
        int s = sorted_src[i];
        float e = el2[s] + er;
        float w = __expf(e > 0.f ? e : NEG * e);
        acc += w * feat2[s * 16 + col];
        wsum += w;
    }
    out[d * 16 + col] = acc / fmaxf(wsum, 1e-9f) + b2[col];
}

// ---------------- launch ----------------

extern "C" void kernel_launch(void* const* d_in, const int* in_sizes, int n_in,
                              void* d_out, int out_size, void* d_ws, size_t ws_size,
                              hipStream_t stream) {
    const float* x   = (const float*)d_in[0];
    const int*   src = (const int*)d_in[1];
    const int*   dst = (const int*)d_in[2];
    const float* W1  = (const float*)d_in[3];
    const float* b1  = (const float*)d_in[4];
    const float* al1 = (const float*)d_in[5];
    const float* ar1 = (const float*)d_in[6];
    const float* W2  = (const float*)d_in[7];
    const float* b2  = (const float*)d_in[8];
    const float* al2 = (const float*)d_in[9];
    const float* ar2 = (const float*)d_in[10];
    float* out = (float*)d_out;

    char* ws = (char*)d_ws;
    size_t off = 0;
    auto alloc = [&](size_t bytes) -> char* {
        char* p = ws + off;
        off += (bytes + 255) & ~(size_t)255;
        return p;
    };
    float* feat1      = (float*)alloc((size_t)N_NODES * HD * 4);
    float* h          = (float*)alloc((size_t)N_NODES * HD * 4);
    float* el1        = (float*)alloc((size_t)N_NODES * 4 * 4);
    float* er1        = (float*)alloc((size_t)N_NODES * 4 * 4);
    float* feat2      = (float*)alloc((size_t)N_NODES * C2 * 4);
    float* el2        = (float*)alloc((size_t)N_NODES * 4);
    float* er2        = (float*)alloc((size_t)N_NODES * 4);
    int*   deg        = (int*)alloc((size_t)N_NODES * 4);
    int*   rowstart   = (int*)alloc((size_t)(N_NODES + 1) * 4);
    int*   cursor     = (int*)alloc((size_t)N_NODES * 4);
    int*   chunksum   = (int*)alloc(128 * 4);
    int*   chunkoff   = (int*)alloc(128 * 4);
    int*   sorted_src = (int*)alloc((size_t)N_EDGES * 4);

    hipMemsetAsync(deg, 0, (size_t)N_NODES * 4, stream);
    k_hist<<<2048, 256, 0, stream>>>(dst, deg);
    k_chunksum<<<NCH, 256, 0, stream>>>(deg, chunksum);
    k_scanchunks<<<1, 128, 0, stream>>>(chunksum, chunkoff);
    k_scanfinal<<<NCH, 256, 0, stream>>>(deg, chunkoff, rowstart, cursor);
    k_scatter<<<2048, 256, 0, stream>>>(src, dst, cursor, sorted_src);
    k_gemm1<<<(N_NODES + 127) / 128, 256, 0, stream>>>(x, W1, al1, ar1, feat1, el1, er1);
    k_agg1<<<N_NODES / 4, 256, 0, stream>>>(rowstart, sorted_src, el1, er1, feat1, b1, h);
    k_gemm2<<<N_NODES / 16, 256, 0, stream>>>(h, W2, al2, ar2, feat2, el2, er2);
    k_agg2<<<N_NODES / 16, 256, 0, stream>>>(rowstart, sorted_src, el2, er2, feat2, b2, out);
}

// Round 3
// 568.864 us; speedup vs baseline: 1.2730x; 1.0129x over previous
//
#include <hip/hip_runtime.h>
#include <hip/hip_fp16.h>

#define N_NODES 50000
#define N_EDGES 1600000
#define FIN 256
#define HD 128          // HEADS*HIDDEN
#define NHEADS 4
#define C2 16           // NUM_CLASSES
#define NEG 0.2f
#define NCH 98          // ceil(50000/512)

__device__ __forceinline__ float elu1(float x) { return x > 0.f ? x : __expf(x) - 1.f; }

// ---------------- CSR build ----------------

__global__ void k_hist(const int* __restrict__ dst, int* __restrict__ deg) {
    int i = blockIdx.x * blockDim.x + threadIdx.x;
    int stride = gridDim.x * blockDim.x;
    for (; i < N_EDGES; i += stride) atomicAdd(&deg[dst[i]], 1);
}

__global__ void k_chunksum(const int* __restrict__ deg, int* __restrict__ chunksum) {
    __shared__ int s[256];
    int b = blockIdx.x, t = threadIdx.x;
    int i0 = b * 512 + t, i1 = i0 + 256;
    int v = 0;
    if (i0 < N_NODES) v += deg[i0];
    if (i1 < N_NODES) v += deg[i1];
    s[t] = v; __syncthreads();
    for (int off = 128; off > 0; off >>= 1) {
        if (t < off) s[t] += s[t + off];
        __syncthreads();
    }
    if (t == 0) chunksum[b] = s[0];
}

__global__ void k_scanchunks(const int* __restrict__ chunksum, int* __restrict__ chunkoff) {
    __shared__ int s[128];
    int t = threadIdx.x;  // blockDim = 128
    int v = (t < NCH) ? chunksum[t] : 0;
    s[t] = v; __syncthreads();
    for (int off = 1; off < 128; off <<= 1) {
        int u = (t >= off) ? s[t - off] : 0;
        __syncthreads();
        s[t] += u;
        __syncthreads();
    }
    chunkoff[t] = s[t] - v;  // exclusive
}

__global__ void k_scanfinal(const int* __restrict__ deg, const int* __restrict__ chunkoff,
                            int* __restrict__ rowstart, int* __restrict__ cursor) {
    __shared__ int s[256];
    int b = blockIdx.x, t = threadIdx.x;
    int i0 = b * 512 + 2 * t, i1 = i0 + 1;
    int a0 = (i0 < N_NODES) ? deg[i0] : 0;
    int a1 = (i1 < N_NODES) ? deg[i1] : 0;
    int pair = a0 + a1;
    s[t] = pair; __syncthreads();
    for (int off = 1; off < 256; off <<= 1) {
        int u = (t >= off) ? s[t - off] : 0;
        __syncthreads();
        s[t] += u;
        __syncthreads();
    }
    int excl = s[t] - pair + chunkoff[b];
    if (i0 <= N_NODES) { rowstart[i0] = excl; if (i0 < N_NODES) cursor[i0] = excl; }
    int e1 = excl + a0;
    if (i1 <= N_NODES) { rowstart[i1] = e1; if (i1 < N_NODES) cursor[i1] = e1; }
}

__global__ void k_scatter(const int* __restrict__ src, const int* __restrict__ dst,
                          int* __restrict__ cursor, int* __restrict__ sorted_src) {
    int i = blockIdx.x * blockDim.x + threadIdx.x;
    int stride = gridDim.x * blockDim.x;
    for (; i < N_EDGES; i += stride) {
        int d = dst[i];
        int pos = atomicAdd(&cursor[d], 1);
        sorted_src[pos] = src[i];
    }
}

// ---------------- Layer 1 GEMM: feat1 = x @ W1 (fp16 out), fused el1/er1 ----------------
// BM=128 nodes x BN=128 cols (all) x BK=16. 256 threads, 8x8 register tile.

__global__ __launch_bounds__(256) void k_gemm1(
        const float* __restrict__ x, const float* __restrict__ W1,
        const float* __restrict__ al1, const float* __restrict__ ar1,
        __half* __restrict__ feat1h, float* __restrict__ el1, float* __restrict__ er1) {
    __shared__ float xs[16 * 128];   // [kk][node] transposed x tile, 8 KB
    __shared__ float ws[16 * 128];   // [kk][col]  native W1 tile,   8 KB
    int tid = threadIdx.x;
    int nb = blockIdx.x * 128;
    int ct = tid & 15;               // col-thread: cols ct*8 .. ct*8+7
    int nt = tid >> 4;               // node-thread: nodes nt*8 .. nt*8+7

    float acc[8][8];
    #pragma unroll
    for (int n = 0; n < 8; n++)
        #pragma unroll
        for (int c = 0; c < 8; c++) acc[n][c] = 0.f;

    int lnode = tid & 127;
    int kg = tid >> 7;               // 0/1: which 8 of the 16 k's this thread stages
    int gnode = nb + lnode; if (gnode >= N_NODES) gnode = N_NODES - 1;  // clamp (stores guarded)
    const float4* xrow = (const float4*)(x + (size_t)gnode * FIN);
    const float4* W14 = (const float4*)W1;

    for (int k0 = 0; k0 < FIN; k0 += 16) {
        float4 a0 = xrow[(k0 >> 2) + kg * 2];
        float4 a1 = xrow[(k0 >> 2) + kg * 2 + 1];
        float4 w0 = W14[(size_t)k0 * 32 + tid];
        float4 w1 = W14[(size_t)k0 * 32 + tid + 256];
        __syncthreads();
        int kb = kg * 8;
        xs[(kb + 0) * 128 + lnode] = a0.x;
        xs[(kb + 1) * 128 + lnode] = a0.y;
        xs[(kb + 2) * 128 + lnode] = a0.z;
        xs[(kb + 3) * 128 + lnode] = a0.w;
        xs[(kb + 4) * 128 + lnode] = a1.x;
        xs[(kb + 5) * 128 + lnode] = a1.y;
        xs[(kb + 6) * 128 + lnode] = a1.z;
        xs[(kb + 7) * 128 + lnode] = a1.w;
        ((float4*)ws)[tid] = w0;
        ((float4*)ws)[tid + 256] = w1;
        __syncthreads();
        #pragma unroll
        for (int kk = 0; kk < 16; kk++) {
            float4 xa = ((const float4*)xs)[kk * 32 + nt * 2];
            float4 xb = ((const float4*)xs)[kk * 32 + nt * 2 + 1];
            float4 wa = ((const float4*)ws)[kk * 32 + ct * 2];
            float4 wb = ((const float4*)ws)[kk * 32 + ct * 2 + 1];
            float xn[8] = {xa.x, xa.y, xa.z, xa.w, xb.x, xb.y, xb.z, xb.w};
            float wc[8] = {wa.x, wa.y, wa.z, wa.w, wb.x, wb.y, wb.z, wb.w};
            #pragma unroll
            for (int n = 0; n < 8; n++)
                #pragma unroll
                for (int c = 0; c < 8; c++)
                    acc[n][c] += xn[n] * wc[c];
        }
    }

    // epilogue: fp16 feat1 stores + fused el/er
    float alv[8], arv[8];
    #pragma unroll
    for (int c = 0; c < 8; c++) { alv[c] = al1[ct * 8 + c]; arv[c] = ar1[ct * 8 + c]; }
    int head = ct >> 2;
    #pragma unroll
    for (int n = 0; n < 8; n++) {
        int node = nb + nt * 8 + n;
        bool ok = node < N_NODES;
        if (ok) {
            __half2 ph[4];
            #pragma unroll
            for (int c2 = 0; c2 < 4; c2++)
                ph[c2] = __floats2half2_rn(acc[n][2 * c2], acc[n][2 * c2 + 1]);
            *(float4*)(feat1h + (size_t)node * HD + ct * 8) = *(float4*)ph;
        }
        float pl = 0.f, pr = 0.f;
        #pragma unroll
        for (int c = 0; c < 8; c++) { pl += acc[n][c] * alv[c]; pr += acc[n][c] * arv[c]; }
        pl += __shfl_xor(pl, 1); pl += __shfl_xor(pl, 2);
        pr += __shfl_xor(pr, 1); pr += __shfl_xor(pr, 2);
        if (ok && (ct & 3) == 0) {
            el1[node * 4 + head] = pl;
            er1[node * 4 + head] = pr;
        }
    }
}

// ---------------- Layer 1 aggregation: one wave per dst node, fp16 gather ----------------

__global__ __launch_bounds__(256) void k_agg1(
        const int* __restrict__ rowstart, const int* __restrict__ sorted_src,
        const float* __restrict__ el1, const float* __restrict__ er1,
        const __half* __restrict__ feat1h, const float* __restrict__ b1,
        float* __restrict__ h) {
    int tid = threadIdx.x;
    int d = blockIdx.x * 4 + (tid >> 6);   // 50000 % 4 == 0
    int lane = tid & 63;
    int head = lane >> 4;                  // lane covers cols [2*lane, 2*lane+1]
    float er = er1[d * 4 + head];
    int start = rowstart[d], end = rowstart[d + 1];
    float ax = 0.f, ay = 0.f, wsum = 0.f;
    const __half2* fbase = (const __half2*)feat1h;
    for (int i = start; i < end; i++) {
        int s = sorted_src[i];
        float e = el1[s * 4 + head] + er;
        float w = __expf(e > 0.f ? e : NEG * e);
        float2 f = __half22float2(fbase[(size_t)s * 64 + lane]);
        ax += w * f.x; ay += w * f.y; wsum += w;
    }
    float inv = 1.f / fmaxf(wsum, 1e-9f);
    int c = lane * 2;
    float vx = elu1(ax * inv + b1[c]);
    float vy = elu1(ay * inv + b1[c + 1]);
    ((float2*)h)[(size_t)d * 64 + lane] = make_float2(vx, vy);
}

// ---------------- Layer 2 GEMM: feat2 = h @ W2, fused el2/er2 ----------------

__global__ __launch_bounds__(256) void k_gemm2(
        const float* __restrict__ h, const float* __restrict__ W2,
        const float* __restrict__ al2, const float* __restrict__ ar2,
        float* __restrict__ feat2, float* __restrict__ el2, float* __restrict__ er2) {
    __shared__ float hs[16 * 132];
    __shared__ float w2t[16 * 132];
    int tid = threadIdx.x;
    int nb = blockIdx.x * 16;  // 50000 % 16 == 0
    for (int idx = tid; idx < 512; idx += 256) {
        int row = idx >> 5, kk = idx & 31;
        ((float4*)(hs + row * 132))[kk] = ((const float4*)h)[(size_t)(nb + row) * 32 + kk];
    }
    for (int idx = tid; idx < 2048; idx += 256) {
        int k = idx >> 4, c = idx & 15;
        w2t[c * 132 + k] = W2[idx];
    }
    __syncthreads();
    int nl = tid >> 4, col = tid & 15;
    const float4* hv = (const float4*)(hs + nl * 132);
    const float4* wv = (const float4*)(w2t + col * 132);
    float acc = 0.f;
    #pragma unroll
    for (int kk = 0; kk < 32; kk++) {
        float4 a = hv[kk], w = wv[kk];
        acc += a.x * w.x + a.y * w.y + a.z * w.z + a.w * w.w;
    }
    int node = nb + nl;
    feat2[node * 16 + col] = acc;
    float pl = acc * al2[col], pr = acc * ar2[col];
    #pragma unroll
    for (int m = 8; m >= 1; m >>= 1) {
        pl += __shfl_xor(pl, m);
        pr += __shfl_xor(pr, m);
    }
    if (col == 0) { el2[node] = pl; er2[node] = pr; }
}

// ---------------- Layer 2 aggregation: 16 lanes per dst node ----------------

__global__ __launch_bounds__(256) void k_agg2(
        const int* __restrict__ rowstart, const int* __restrict__ sorted_src,
        const float* __restrict__ el2, const float* __restrict__ er2,
        const float* __restrict__ feat2, const float* __restrict__ b2,
        float* __restrict__ out) {
    int tid = threadIdx.x;
    int d = blockIdx.x * 16 + (tid >> 4);  // 50000 % 16 == 0
    int col = tid & 15;
    float er = er2[d];
    int start = rowstart[d], end = rowstart[d + 1];
    float acc = 0.f, wsum = 0.f;
    for (int i = start; i < end; i++) {
        int s = sorted_src[i];
        float e = el2[s] + er;
        float w = __expf(e > 0.f ? e : NEG * e);
        acc += w * feat2[s * 16 + col];
        wsum += w;
    }
    out[d * 16 + col] = acc / fmaxf(wsum, 1e-9f) + b2[col];
}

// ---------------- launch ----------------

extern "C" void kernel_launch(void* const* d_in, const int* in_sizes, int n_in,
                              void* d_out, int out_size, void* d_ws, size_t ws_size,
                              hipStream_t stream) {
    const float* x   = (const float*)d_in[0];
    const int*   src = (const int*)d_in[1];
    const int*   dst = (const int*)d_in[2];
    const float* W1  = (const float*)d_in[3];
    const float* b1  = (const float*)d_in[4];
    const float* al1 = (const float*)d_in[5];
    const float* ar1 = (const float*)d_in[6];
    const float* W2  = (const float*)d_in[7];
    const float* b2  = (const float*)d_in[8];
    const float* al2 = (const float*)d_in[9];
    const float* ar2 = (const float*)d_in[10];
    float* out = (float*)d_out;

    char* ws = (char*)d_ws;
    size_t off = 0;
    auto alloc = [&](size_t bytes) -> char* {
        char* p = ws + off;
        off += (bytes + 255) & ~(size_t)255;
        return p;
    };
    __half* feat1h    = (__half*)alloc((size_t)N_NODES * HD * 2);
    float* h          = (float*)alloc((size_t)N_NODES * HD * 4);
    float* el1        = (float*)alloc((size_t)N_NODES * 4 * 4);
    float* er1        = (float*)alloc((size_t)N_NODES * 4 * 4);
    float* feat2      = (float*)alloc((size_t)N_NODES * C2 * 4);
    float* el2        = (float*)alloc((size_t)N_NODES * 4);
    float* er2        = (float*)alloc((size_t)N_NODES * 4);
    int*   deg        = (int*)alloc((size_t)N_NODES * 4);
    int*   rowstart   = (int*)alloc((size_t)(N_NODES + 1) * 4);
    int*   cursor     = (int*)alloc((size_t)N_NODES * 4);
    int*   chunksum   = (int*)alloc(128 * 4);
    int*   chunkoff   = (int*)alloc(128 * 4);
    int*   sorted_src = (int*)alloc((size_t)N_EDGES * 4);

    hipMemsetAsync(deg, 0, (size_t)N_NODES * 4, stream);
    k_hist<<<2048, 256, 0, stream>>>(dst, deg);
    k_chunksum<<<NCH, 256, 0, stream>>>(deg, chunksum);
    k_scanchunks<<<1, 128, 0, stream>>>(chunksum, chunkoff);
    k_scanfinal<<<NCH, 256, 0, stream>>>(deg, chunkoff, rowstart, cursor);
    k_scatter<<<2048, 256, 0, stream>>>(src, dst, cursor, sorted_src);
    k_gemm1<<<(N_NODES + 127) / 128, 256, 0, stream>>>(x, W1, al1, ar1, feat1h, el1, er1);
    k_agg1<<<N_NODES / 4, 256, 0, stream>>>(rowstart, sorted_src, el1, er1, feat1h, b1, h);
    k_gemm2<<<N_NODES / 16, 256, 0, stream>>>(h, W2, al2, ar2, feat2, el2, er2);
    k_agg2<<<N_NODES / 16, 256, 0, stream>>>(rowstart, sorted_src, el2, er2, feat2, b2, out);
}

// Round 4
// 405.595 us; speedup vs baseline: 1.7854x; 1.4025x over previous
//
#include <hip/hip_runtime.h>
#include <hip/hip_fp16.h>

#define N_NODES 50000
#define N_EDGES 1600000
#define FIN 256
#define HD 128          // HEADS*HIDDEN
#define NHEADS 4
#define C2 16           // NUM_CLASSES
#define NEG 0.2f
#define NCH 98          // ceil(50000/512)

__device__ __forceinline__ float elu1(float x) { return x > 0.f ? x : __expf(x) - 1.f; }
__device__ __forceinline__ float lexp(float e) { return __expf(e > 0.f ? e : NEG * e); }

// ---------------- CSR build ----------------

__global__ void k_hist(const int* __restrict__ dst, int* __restrict__ deg) {
    int i = blockIdx.x * blockDim.x + threadIdx.x;
    int stride = gridDim.x * blockDim.x;
    for (; i < N_EDGES; i += stride) atomicAdd(&deg[dst[i]], 1);
}

__global__ void k_chunksum(const int* __restrict__ deg, int* __restrict__ chunksum) {
    __shared__ int s[256];
    int b = blockIdx.x, t = threadIdx.x;
    int i0 = b * 512 + t, i1 = i0 + 256;
    int v = 0;
    if (i0 < N_NODES) v += deg[i0];
    if (i1 < N_NODES) v += deg[i1];
    s[t] = v; __syncthreads();
    for (int off = 128; off > 0; off >>= 1) {
        if (t < off) s[t] += s[t + off];
        __syncthreads();
    }
    if (t == 0) chunksum[b] = s[0];
}

__global__ void k_scanchunks(const int* __restrict__ chunksum, int* __restrict__ chunkoff) {
    __shared__ int s[128];
    int t = threadIdx.x;  // blockDim = 128
    int v = (t < NCH) ? chunksum[t] : 0;
    s[t] = v; __syncthreads();
    for (int off = 1; off < 128; off <<= 1) {
        int u = (t >= off) ? s[t - off] : 0;
        __syncthreads();
        s[t] += u;
        __syncthreads();
    }
    chunkoff[t] = s[t] - v;  // exclusive
}

__global__ void k_scanfinal(const int* __restrict__ deg, const int* __restrict__ chunkoff,
                            int* __restrict__ rowstart, int* __restrict__ cursor) {
    __shared__ int s[256];
    int b = blockIdx.x, t = threadIdx.x;
    int i0 = b * 512 + 2 * t, i1 = i0 + 1;
    int a0 = (i0 < N_NODES) ? deg[i0] : 0;
    int a1 = (i1 < N_NODES) ? deg[i1] : 0;
    int pair = a0 + a1;
    s[t] = pair; __syncthreads();
    for (int off = 1; off < 256; off <<= 1) {
        int u = (t >= off) ? s[t - off] : 0;
        __syncthreads();
        s[t] += u;
        __syncthreads();
    }
    int excl = s[t] - pair + chunkoff[b];
    if (i0 <= N_NODES) { rowstart[i0] = excl; if (i0 < N_NODES) cursor[i0] = excl; }
    int e1 = excl + a0;
    if (i1 <= N_NODES) { rowstart[i1] = e1; if (i1 < N_NODES) cursor[i1] = e1; }
}

// Scatter + fused layer-1 edge weights: w1buf[pos] = exp(leaky(el1[s]+er1[d])) per head.
__global__ void k_scatter(const int* __restrict__ src, const int* __restrict__ dst,
                          int* __restrict__ cursor,
                          const float* __restrict__ el1, const float* __restrict__ er1,
                          int* __restrict__ sorted_src, float4* __restrict__ w1buf) {
    int i = blockIdx.x * blockDim.x + threadIdx.x;
    int stride = gridDim.x * blockDim.x;
    for (; i < N_EDGES; i += stride) {
        int s = src[i], d = dst[i];
        int pos = atomicAdd(&cursor[d], 1);
        sorted_src[pos] = s;
        float4 el = ((const float4*)el1)[s];
        float4 er = ((const float4*)er1)[d];
        float4 w;
        w.x = lexp(el.x + er.x);
        w.y = lexp(el.y + er.y);
        w.z = lexp(el.z + er.z);
        w.w = lexp(el.w + er.w);
        w1buf[pos] = w;
    }
}

// ---------------- Layer 1 GEMM: feat1 = x @ W1 (fp16 out), fused el1/er1 ----------------

__global__ __launch_bounds__(256) void k_gemm1(
        const float* __restrict__ x, const float* __restrict__ W1,
        const float* __restrict__ al1, const float* __restrict__ ar1,
        __half* __restrict__ feat1h, float* __restrict__ el1, float* __restrict__ er1) {
    __shared__ float xs[16 * 128];   // [kk][node] transposed x tile, 8 KB
    __shared__ float ws[16 * 128];   // [kk][col]  native W1 tile,   8 KB
    int tid = threadIdx.x;
    int nb = blockIdx.x * 128;
    int ct = tid & 15;               // col-thread: cols ct*8 .. ct*8+7
    int nt = tid >> 4;               // node-thread: nodes nt*8 .. nt*8+7

    float acc[8][8];
    #pragma unroll
    for (int n = 0; n < 8; n++)
        #pragma unroll
        for (int c = 0; c < 8; c++) acc[n][c] = 0.f;

    int lnode = tid & 127;
    int kg = tid >> 7;               // 0/1: which 8 of the 16 k's this thread stages
    int gnode = nb + lnode; if (gnode >= N_NODES) gnode = N_NODES - 1;
    const float4* xrow = (const float4*)(x + (size_t)gnode * FIN);
    const float4* W14 = (const float4*)W1;

    for (int k0 = 0; k0 < FIN; k0 += 16) {
        float4 a0 = xrow[(k0 >> 2) + kg * 2];
        float4 a1 = xrow[(k0 >> 2) + kg * 2 + 1];
        float4 w0 = W14[(size_t)k0 * 32 + tid];
        float4 w1 = W14[(size_t)k0 * 32 + tid + 256];
        __syncthreads();
        int kb = kg * 8;
        xs[(kb + 0) * 128 + lnode] = a0.x;
        xs[(kb + 1) * 128 + lnode] = a0.y;
        xs[(kb + 2) * 128 + lnode] = a0.z;
        xs[(kb + 3) * 128 + lnode] = a0.w;
        xs[(kb + 4) * 128 + lnode] = a1.x;
        xs[(kb + 5) * 128 + lnode] = a1.y;
        xs[(kb + 6) * 128 + lnode] = a1.z;
        xs[(kb + 7) * 128 + lnode] = a1.w;
        ((float4*)ws)[tid] = w0;
        ((float4*)ws)[tid + 256] = w1;
        __syncthreads();
        #pragma unroll
        for (int kk = 0; kk < 16; kk++) {
            float4 xa = ((const float4*)xs)[kk * 32 + nt * 2];
            float4 xb = ((const float4*)xs)[kk * 32 + nt * 2 + 1];
            float4 wa = ((const float4*)ws)[kk * 32 + ct * 2];
            float4 wb = ((const float4*)ws)[kk * 32 + ct * 2 + 1];
            float xn[8] = {xa.x, xa.y, xa.z, xa.w, xb.x, xb.y, xb.z, xb.w};
            float wc[8] = {wa.x, wa.y, wa.z, wa.w, wb.x, wb.y, wb.z, wb.w};
            #pragma unroll
            for (int n = 0; n < 8; n++)
                #pragma unroll
                for (int c = 0; c < 8; c++)
                    acc[n][c] += xn[n] * wc[c];
        }
    }

    float alv[8], arv[8];
    #pragma unroll
    for (int c = 0; c < 8; c++) { alv[c] = al1[ct * 8 + c]; arv[c] = ar1[ct * 8 + c]; }
    int head = ct >> 2;
    #pragma unroll
    for (int n = 0; n < 8; n++) {
        int node = nb + nt * 8 + n;
        bool ok = node < N_NODES;
        if (ok) {
            __half2 ph[4];
            #pragma unroll
            for (int c2 = 0; c2 < 4; c2++)
                ph[c2] = __floats2half2_rn(acc[n][2 * c2], acc[n][2 * c2 + 1]);
            *(float4*)(feat1h + (size_t)node * HD + ct * 8) = *(float4*)ph;
        }
        float pl = 0.f, pr = 0.f;
        #pragma unroll
        for (int c = 0; c < 8; c++) { pl += acc[n][c] * alv[c]; pr += acc[n][c] * arv[c]; }
        pl += __shfl_xor(pl, 1); pl += __shfl_xor(pl, 2);
        pr += __shfl_xor(pr, 1); pr += __shfl_xor(pr, 2);
        if (ok && (ct & 3) == 0) {
            el1[node * 4 + head] = pl;
            er1[node * 4 + head] = pr;
        }
    }
}

// ---------------- Layer 1 aggregation: wave per dst, 4 edges x 16 col-lanes ----------------

__global__ __launch_bounds__(256) void k_agg1(
        const int* __restrict__ rowstart, const int* __restrict__ sorted_src,
        const float* __restrict__ w1buf, const __half* __restrict__ feat1h,
        const float* __restrict__ b1, float* __restrict__ h) {
    int tid = threadIdx.x;
    int d = blockIdx.x * 4 + (tid >> 6);   // 50000 % 4 == 0
    int lane = tid & 63;
    int eg = lane >> 4;                    // edge group 0..3
    int cl = lane & 15;                    // col-lane: cols 8*cl..8*cl+7
    int head = cl >> 2;
    int start = rowstart[d], end = rowstart[d + 1];
    float acc[8];
    #pragma unroll
    for (int k = 0; k < 8; k++) acc[k] = 0.f;
    float wsum = 0.f;

    for (int i = start; i < end; i += 8) {
        int e0 = i + eg, e1 = i + 4 + eg;
        bool ok0 = e0 < end, ok1 = e1 < end;
        int e0c = ok0 ? e0 : end - 1;
        int e1c = ok1 ? e1 : end - 1;
        int s0 = sorted_src[e0c];
        int s1 = sorted_src[e1c];
        float w0r = w1buf[e0c * 4 + head];
        float w1r = w1buf[e1c * 4 + head];
        float4 r0 = *(const float4*)(feat1h + (size_t)s0 * HD + cl * 8);
        float4 r1 = *(const float4*)(feat1h + (size_t)s1 * HD + cl * 8);
        float w0 = ok0 ? w0r : 0.f;
        float w1 = ok1 ? w1r : 0.f;
        const __half2* p0 = (const __half2*)&r0;
        const __half2* p1 = (const __half2*)&r1;
        #pragma unroll
        for (int q = 0; q < 4; q++) {
            float2 f0 = __half22float2(p0[q]);
            float2 f1 = __half22float2(p1[q]);
            acc[2 * q]     += w0 * f0.x + w1 * f1.x;
            acc[2 * q + 1] += w0 * f0.y + w1 * f1.y;
        }
        wsum += w0 + w1;
    }
    #pragma unroll
    for (int k = 0; k < 8; k++) {
        acc[k] += __shfl_xor(acc[k], 16);
        acc[k] += __shfl_xor(acc[k], 32);
    }
    wsum += __shfl_xor(wsum, 16);
    wsum += __shfl_xor(wsum, 32);
    if (eg == 0) {
        float inv = 1.f / fmaxf(wsum, 1e-9f);
        float v[8];
        #pragma unroll
        for (int k = 0; k < 8; k++) v[k] = elu1(acc[k] * inv + b1[cl * 8 + k]);
        float4* hp = (float4*)(h + (size_t)d * HD + cl * 8);
        hp[0] = make_float4(v[0], v[1], v[2], v[3]);
        hp[1] = make_float4(v[4], v[5], v[6], v[7]);
    }
}

// ---------------- Layer 2 GEMM: feat2 = h @ W2, fused el2/er2 ----------------

__global__ __launch_bounds__(256) void k_gemm2(
        const float* __restrict__ h, const float* __restrict__ W2,
        const float* __restrict__ al2, const float* __restrict__ ar2,
        float* __restrict__ feat2, float* __restrict__ el2, float* __restrict__ er2) {
    __shared__ float hs[16 * 132];
    __shared__ float w2t[16 * 132];
    int tid = threadIdx.x;
    int nb = blockIdx.x * 16;  // 50000 % 16 == 0
    for (int idx = tid; idx < 512; idx += 256) {
        int row = idx >> 5, kk = idx & 31;
        ((float4*)(hs + row * 132))[kk] = ((const float4*)h)[(size_t)(nb + row) * 32 + kk];
    }
    for (int idx = tid; idx < 2048; idx += 256) {
        int k = idx >> 4, c = idx & 15;
        w2t[c * 132 + k] = W2[idx];
    }
    __syncthreads();
    int nl = tid >> 4, col = tid & 15;
    const float4* hv = (const float4*)(hs + nl * 132);
    const float4* wv = (const float4*)(w2t + col * 132);
    float acc = 0.f;
    #pragma unroll
    for (int kk = 0; kk < 32; kk++) {
        float4 a = hv[kk], w = wv[kk];
        acc += a.x * w.x + a.y * w.y + a.z * w.z + a.w * w.w;
    }
    int node = nb + nl;
    feat2[node * 16 + col] = acc;
    float pl = acc * al2[col], pr = acc * ar2[col];
    #pragma unroll
    for (int m = 8; m >= 1; m >>= 1) {
        pl += __shfl_xor(pl, m);
        pr += __shfl_xor(pr, m);
    }
    if (col == 0) { el2[node] = pl; er2[node] = pr; }
}

// ---------------- Layer 2 aggregation: wave per dst, 16 edges x 4 col-lanes ----------------

__global__ __launch_bounds__(256) void k_agg2(
        const int* __restrict__ rowstart, const int* __restrict__ sorted_src,
        const float* __restrict__ el2, const float* __restrict__ er2,
        const float* __restrict__ feat2, const float* __restrict__ b2,
        float* __restrict__ out) {
    int tid = threadIdx.x;
    int d = blockIdx.x * 4 + (tid >> 6);   // 50000 % 4 == 0
    int lane = tid & 63;
    int eg = lane >> 2;                    // edge group 0..15
    int cq = lane & 3;                     // cols 4*cq..4*cq+3
    float er = er2[d];
    int start = rowstart[d], end = rowstart[d + 1];
    float4 acc = make_float4(0.f, 0.f, 0.f, 0.f);
    float wsum = 0.f;
    for (int i = start; i < end; i += 16) {
        int e = i + eg;
        bool ok = e < end;
        int ec = ok ? e : end - 1;
        int s = sorted_src[ec];
        float elv = el2[s];
        float4 f = ((const float4*)feat2)[(size_t)s * 4 + cq];
        float ev = elv + er;
        float wr = __expf(ev > 0.f ? ev : NEG * ev);
        float w = ok ? wr : 0.f;
        acc.x += w * f.x; acc.y += w * f.y; acc.z += w * f.z; acc.w += w * f.w;
        wsum += w;
    }
    #pragma unroll
    for (int m = 4; m <= 32; m <<= 1) {
        acc.x += __shfl_xor(acc.x, m);
        acc.y += __shfl_xor(acc.y, m);
        acc.z += __shfl_xor(acc.z, m);
        acc.w += __shfl_xor(acc.w, m);
        wsum  += __shfl_xor(wsum, m);
    }
    if (lane < 4) {
        float inv = 1.f / fmaxf(wsum, 1e-9f);
        float4 bv = ((const float4*)b2)[cq];
        float4 o = make_float4(acc.x * inv + bv.x, acc.y * inv + bv.y,
                               acc.z * inv + bv.z, acc.w * inv + bv.w);
        ((float4*)out)[(size_t)d * 4 + cq] = o;
    }
}

// ---------------- launch ----------------

extern "C" void kernel_launch(void* const* d_in, const int* in_sizes, int n_in,
                              void* d_out, int out_size, void* d_ws, size_t ws_size,
                              hipStream_t stream) {
    const float* x   = (const float*)d_in[0];
    const int*   src = (const int*)d_in[1];
    const int*   dst = (const int*)d_in[2];
    const float* W1  = (const float*)d_in[3];
    const float* b1  = (const float*)d_in[4];
    const float* al1 = (const float*)d_in[5];
    const float* ar1 = (const float*)d_in[6];
    const float* W2  = (const float*)d_in[7];
    const float* b2  = (const float*)d_in[8];
    const float* al2 = (const float*)d_in[9];
    const float* ar2 = (const float*)d_in[10];
    float* out = (float*)d_out;

    char* ws = (char*)d_ws;
    size_t off = 0;
    auto alloc = [&](size_t bytes) -> char* {
        char* p = ws + off;
        off += (bytes + 255) & ~(size_t)255;
        return p;
    };
    __half* feat1h    = (__half*)alloc((size_t)N_NODES * HD * 2);
    float* h          = (float*)alloc((size_t)N_NODES * HD * 4);
    float* el1        = (float*)alloc((size_t)N_NODES * 4 * 4);
    float* er1        = (float*)alloc((size_t)N_NODES * 4 * 4);
    float* feat2      = (float*)alloc((size_t)N_NODES * C2 * 4);
    float* el2        = (float*)alloc((size_t)N_NODES * 4);
    float* er2        = (float*)alloc((size_t)N_NODES * 4);
    int*   deg        = (int*)alloc((size_t)N_NODES * 4);
    int*   rowstart   = (int*)alloc((size_t)(N_NODES + 1) * 4);
    int*   cursor     = (int*)alloc((size_t)N_NODES * 4);
    int*   chunksum   = (int*)alloc(128 * 4);
    int*   chunkoff   = (int*)alloc(128 * 4);
    int*   sorted_src = (int*)alloc((size_t)N_EDGES * 4);
    float* w1buf      = (float*)alloc((size_t)N_EDGES * 4 * 4);

    hipMemsetAsync(deg, 0, (size_t)N_NODES * 4, stream);
    k_hist<<<2048, 256, 0, stream>>>(dst, deg);
    k_chunksum<<<NCH, 256, 0, stream>>>(deg, chunksum);
    k_scanchunks<<<1, 128, 0, stream>>>(chunksum, chunkoff);
    k_scanfinal<<<NCH, 256, 0, stream>>>(deg, chunkoff, rowstart, cursor);
    k_gemm1<<<(N_NODES + 127) / 128, 256, 0, stream>>>(x, W1, al1, ar1, feat1h, el1, er1);
    k_scatter<<<2048, 256, 0, stream>>>(src, dst, cursor, el1, er1, sorted_src, (float4*)w1buf);
    k_agg1<<<N_NODES / 4, 256, 0, stream>>>(rowstart, sorted_src, w1buf, feat1h, b1, h);
    k_gemm2<<<N_NODES / 16, 256, 0, stream>>>(h, W2, al2, ar2, feat2, el2, er2);
    k_agg2<<<N_NODES / 4, 256, 0, stream>>>(rowstart, sorted_src, el2, er2, feat2, b2, out);
}